// Round 15
// baseline (31.656 us; speedup 1.0000x reference)
//
#include <hip/hip_runtime.h>

#define NSTROKES 64
#define NSAMP    50
#define CANVAS   512
#define HW       (CANVAS * CANVAS)
#define TPB      1024                  // 512 px x 2 stroke-groups, 16 waves
#define SPW      (NSTROKES / 16)       // 4 strokes per wave (stage A)
#define LSTRIDE  64                    // float2 slots per stroke list

// ---------------------------------------------------------------------------
// ROUND-15 PROBE: round-10 kernel (best known, 18.08us) with stage B executed
// 3x. Calls 2-3 take fx / span bounds through asm-obfuscated registers so
// ballots, control flow and loop math must fully re-execute; their results
// are consumed by empty asm sinks. Call 1's result is written out -> output
// bit-identical to round 10.   dur = base + 2*stageB_marginal.
// ---------------------------------------------------------------------------

__device__ __forceinline__ float4 stage_b(
    const float2* __restrict__ slist, const float4* __restrict__ scull,
    const float4* __restrict__ scol,
    float fx, float fy, int sbase, int lane, float span_lo, float span_hi)
{
    float4 cbl = scull[sbase + (lane & 31)];
    bool alive = (cbl.w > 0.0f) && (cbl.x <= span_hi) && (cbl.y >= span_lo);
    unsigned int live = (unsigned int)__ballot(alive);   // low 32 == high 32

    float A = 1.0f, br = 0.0f, bg = 0.0f, bb = 0.0f;

    while (live) {
        const int s0 = sbase + (__ffs(live) - 1);
        live &= live - 1u;
        const bool has1 = (live != 0u);
        const int s1 = has1 ? (sbase + (__ffs(live) - 1)) : s0;
        if (has1) live &= live - 1u;

        float4 cb0  = scull[s0];
        float4 cb1  = scull[s1];
        float4 col0 = scol [s0];
        float4 col1 = scol [s1];
        const int   kc0 = (int)cb0.w;
        const int   kc1 = has1 ? (int)cb1.w : 0;
        const float w0  = cb0.z;
        const float w1  = cb1.z;

        float m0 = 1e30f, m1 = 1e30f;
        const float4* L0 = (const float4*)(slist + s0 * LSTRIDE);
        const float4* L1 = (const float4*)(slist + s1 * LSTRIDE);

        const int kmax = kc0 > kc1 ? kc0 : kc1;
        for (int j = 0; j < kmax; j += 4) {        // sentinel-padded to 4
            if (j < kc0) {                          // wave-uniform branch
                float4 q0 = L0[(j >> 1)];
                float4 q1 = L0[(j >> 1) + 1];
                float dy0 = fy - q0.y, dy1 = fy - q0.w;
                float dy2 = fy - q1.y, dy3 = fy - q1.w;
                float d0  = fx - q0.x, d1  = fx - q0.z;
                float d2  = fx - q1.x, d3  = fx - q1.z;
                float a01 = fminf(fmaf(d0, d0, dy0*dy0), fmaf(d1, d1, dy1*dy1));
                float a23 = fminf(fmaf(d2, d2, dy2*dy2), fmaf(d3, d3, dy3*dy3));
                m0 = fminf(fminf(a01, a23), m0);
            }
            if (j < kc1) {
                float4 q0 = L1[(j >> 1)];
                float4 q1 = L1[(j >> 1) + 1];
                float dy0 = fy - q0.y, dy1 = fy - q0.w;
                float dy2 = fy - q1.y, dy3 = fy - q1.w;
                float d0  = fx - q0.x, d1  = fx - q0.z;
                float d2  = fx - q1.x, d3  = fx - q1.z;
                float a01 = fminf(fmaf(d0, d0, dy0*dy0), fmaf(d1, d1, dy1*dy1));
                float a23 = fminf(fmaf(d2, d2, dy2*dy2), fmaf(d3, d3, dy3*dy3));
                m1 = fminf(fminf(a01, a23), m1);
            }
        }

        float al0 = __builtin_amdgcn_rcpf(1.0f + __expf(2.0f * (sqrtf(m0) - w0)));
        float al1 = __builtin_amdgcn_rcpf(1.0f + __expf(2.0f * (sqrtf(m1) - w1)));

        A  *= (1.0f - al0);
        br  = fmaf(al0, col0.x - br, br);
        bg  = fmaf(al0, col0.y - bg, bg);
        bb  = fmaf(al0, col0.z - bb, bb);
        if (has1) {
            A  *= (1.0f - al1);
            br  = fmaf(al1, col1.x - br, br);
            bg  = fmaf(al1, col1.y - bg, bg);
            bb  = fmaf(al1, col1.z - bb, bb);
        }
    }
    return make_float4(A, br, bg, bb);
}

__global__ __launch_bounds__(TPB, 8) void raster_fused_kernel(
    const float* __restrict__ strokes,   // (64,4,2)
    const float* __restrict__ widths,    // (64,)
    const float* __restrict__ colors,    // (64,3)
    float* __restrict__ out)             // (1,3,512,512)
{
    __shared__ __align__(16) float2 slist[NSTROKES * LSTRIDE];  // 32 KB
    __shared__ float4 scull[NSTROKES];   // xmin-cut, xmax+cut, w, cnt
    __shared__ float4 scol [NSTROKES];   // r,g,b,pad

    const int tid  = threadIdx.x;
    const int wave = tid >> 6;
    const int lane = tid & 63;
    const int px   = tid & 511;
    const int grp  = tid >> 9;           // 0: strokes 0-31, 1: strokes 32-63
    const int y    = blockIdx.x;
    const float fy = (float)y;

    // ---- stage A: compaction, SPW strokes per wave, lane = sample index
    #pragma unroll
    for (int i = 0; i < SPW; ++i) {
        const int s = wave * SPW + i;        // stroke id 0..63

        float4 a = ((const float4*)strokes)[s * 2];       // p0x,p0y,p1x,p1y
        float4 b = ((const float4*)strokes)[s * 2 + 1];   // p2x,p2y,p3x,p3y
        const float S = (float)CANVAS;
        float c0x = a.x * S;
        float c1x = 3.0f * (a.z - a.x) * S;
        float c2x = 3.0f * (b.x - 2.0f * a.z + a.x) * S;
        float c3x = (b.z - 3.0f * b.x + 3.0f * a.z - a.x) * S;
        float c0y = a.y * S;
        float c1y = 3.0f * (a.w - a.y) * S;
        float c2y = 3.0f * (b.y - 2.0f * a.w + a.y) * S;
        float c3y = (b.w - 3.0f * b.y + 3.0f * a.w - a.y) * S;

        float w   = widths[s];
        float cut = w + 10.0f;               // alpha <= sigmoid(-20) ~ 2e-9 beyond

        float t   = (float)lane * (1.0f / (float)(NSAMP - 1));
        float px_ = fmaf(fmaf(fmaf(c3x, t, c2x), t, c1x), t, c0x);
        float py_ = fmaf(fmaf(fmaf(c3y, t, c2y), t, c1y), t, c0y);

        bool keep = (lane < NSAMP) && (fabsf(py_ - fy) <= cut);
        unsigned long long mask = __ballot(keep);
        int idx = __popcll(mask & ((1ull << lane) - 1ull));
        if (keep) {
            slist[s * LSTRIDE + idx] = make_float2(px_, py_);
        } else if (lane >= NSAMP) {
            // lanes 50..63: idx == kc for all -> consecutive sentinel slots
            slist[s * LSTRIDE + idx + (lane - NSAMP)] = make_float2(1e15f, 1e15f);
        }

        if (mask) {
            float vmn = keep ? px_ : 1e30f;
            float vmx = keep ? px_ : -1e30f;
            #pragma unroll
            for (int off = 32; off; off >>= 1) {
                vmn = fminf(vmn, __shfl_xor(vmn, off));
                vmx = fmaxf(vmx, __shfl_xor(vmx, off));
            }
            if (lane == 0) {
                scull[s] = make_float4(vmn - cut, vmx + cut, w,
                                       (float)__popcll(mask));
                scol [s] = make_float4(colors[3*s], colors[3*s+1],
                                       colors[3*s+2], 0.0f);
            }
        } else if (lane == 0) {
            scull[s] = make_float4(0.0f, 0.0f, w, 0.0f);   // cnt=0 -> culled
        }
    }
    __syncthreads();

    // ---- stage B pass 1 (the real one)
    const float fx      = (float)px;
    const float span_lo = (float)((wave & 7) << 6);
    const float span_hi = span_lo + 63.0f;
    const int   sbase   = grp << 5;

    float4 r1 = stage_b(slist, scull, scol, fx, fy, sbase, lane,
                        span_lo, span_hi);

    // ---- probe passes 2 and 3: opaque fx/span bounds defeat CSE and force
    //      full re-execution (ballots, loops, sigmoids); results sunk.
    {
        float fxo = fx, slo = span_lo, shi = span_hi;
        asm volatile("" : "+v"(fxo), "+v"(slo), "+v"(shi));
        float4 r2 = stage_b(slist, scull, scol, fxo, fy, sbase, lane, slo, shi);
        asm volatile("" :: "v"(r2.x), "v"(r2.y), "v"(r2.z), "v"(r2.w));
        asm volatile("" : "+v"(fxo), "+v"(slo), "+v"(shi));
        float4 r3 = stage_b(slist, scull, scol, fxo, fy, sbase, lane, slo, shi);
        asm volatile("" :: "v"(r3.x), "v"(r3.y), "v"(r3.z), "v"(r3.w));
    }

    const float A = r1.x, br = r1.y, bg = r1.z, bb = r1.w;

    // ---- combine: g0 publishes (A,B) via LDS (slist is dead), g1 folds
    __syncthreads();
    float4* xfer = (float4*)slist;           // 512 x float4 = 8 KB
    if (grp == 0) {
        xfer[px] = make_float4(A, br, bg, bb);
    }
    __syncthreads();
    if (grp == 1) {
        float4 g0 = xfer[px];
        // white canvas: c0 = A0*1 + B0; then c = A1*c0 + B1
        float cr = fmaf(A, g0.x + g0.y, br);
        float cg = fmaf(A, g0.x + g0.z, bg);
        float cb = fmaf(A, g0.x + g0.w, bb);
        const int base = y * CANVAS + px;
        out[0*HW + base] = cr;
        out[1*HW + base] = cg;
        out[2*HW + base] = cb;
    }
}

extern "C" void kernel_launch(void* const* d_in, const int* in_sizes, int n_in,
                              void* d_out, int out_size, void* d_ws, size_t ws_size,
                              hipStream_t stream) {
    const float* strokes = (const float*)d_in[0];
    const float* widths  = (const float*)d_in[1];
    const float* colors  = (const float*)d_in[2];
    float* out = (float*)d_out;

    raster_fused_kernel<<<dim3(CANVAS), dim3(TPB), 0, stream>>>(
        strokes, widths, colors, out);
}

// Round 16
// 21.623 us; speedup vs baseline: 1.4640x; 1.4640x over previous
//
#include <hip/hip_runtime.h>

#define NSTROKES 64
#define NSAMP    50
#define CANVAS   512
#define HW       (CANVAS * CANVAS)
#define LSTRIDE  64                    // float2 slots per (row,stroke) list

// ws layout: ws_list [512][64][LSTRIDE] float2 (16 MB), then ws_hdr [512][64]
// float4 (2 MB): (xmin-cut, xmax+cut, w, cnt) -- same format as r10's scull.
#define WS_LIST_BYTES ((size_t)CANVAS * NSTROKES * LSTRIDE * sizeof(float2))
#define WS_NEED       (WS_LIST_BYTES + (size_t)CANVAS * NSTROKES * sizeof(float4))

// ---------------------------------------------------------------------------
// k1: one thread per (row, stroke). Horner-sample the stroke, keep samples
// with |py-fy| <= w+10, append sequentially (t-order == ballot-compaction
// order -> bit-identical lists), track x-range, write header + 4 sentinels.
// ---------------------------------------------------------------------------
__global__ __launch_bounds__(256) void sample_kernel(
    const float* __restrict__ strokes,   // (64,4,2)
    const float* __restrict__ widths,    // (64,)
    float2* __restrict__ ws_list,
    float4* __restrict__ ws_hdr)
{
    const int t   = blockIdx.x * 256 + threadIdx.x;   // 32768
    const int row = t >> 6;
    const int s   = t & 63;
    const float fy = (float)row;

    float4 a = ((const float4*)strokes)[s * 2];       // p0x,p0y,p1x,p1y
    float4 b = ((const float4*)strokes)[s * 2 + 1];   // p2x,p2y,p3x,p3y
    const float S = (float)CANVAS;
    float c0x = a.x * S;
    float c1x = 3.0f * (a.z - a.x) * S;
    float c2x = 3.0f * (b.x - 2.0f * a.z + a.x) * S;
    float c3x = (b.z - 3.0f * b.x + 3.0f * a.z - a.x) * S;
    float c0y = a.y * S;
    float c1y = 3.0f * (a.w - a.y) * S;
    float c2y = 3.0f * (b.y - 2.0f * a.w + a.y) * S;
    float c3y = (b.w - 3.0f * b.y + 3.0f * a.w - a.y) * S;

    float w   = widths[s];
    float cut = w + 10.0f;               // alpha <= sigmoid(-20) ~ 2e-9 beyond

    float2* L = ws_list + ((size_t)row * NSTROKES + s) * LSTRIDE;
    int cnt = 0;
    float xmn = 1e30f, xmx = -1e30f;

    #pragma unroll 10
    for (int j = 0; j < NSAMP; ++j) {
        float tt = (float)j * (1.0f / (float)(NSAMP - 1));
        float px = fmaf(fmaf(fmaf(c3x, tt, c2x), tt, c1x), tt, c0x);
        float py = fmaf(fmaf(fmaf(c3y, tt, c2y), tt, c1y), tt, c0y);
        if (fabsf(py - fy) <= cut) {
            L[cnt] = make_float2(px, py);
            ++cnt;
            xmn = fminf(xmn, px);
            xmx = fmaxf(xmx, px);
        }
    }
    // 4 sentinels cover the 4-wide loop's over-read (max index kc+2)
    L[cnt]     = make_float2(1e15f, 1e15f);
    L[cnt + 1] = make_float2(1e15f, 1e15f);
    L[cnt + 2] = make_float2(1e15f, 1e15f);
    L[cnt + 3] = make_float2(1e15f, 1e15f);

    ws_hdr[row * NSTROKES + s] =
        make_float4(xmn - cut, xmx + cut, w, (float)cnt);  // cnt=0 -> culled
}

// ---------------------------------------------------------------------------
// k2: one block per (row, half-row). 512 threads = 256 px x 2 stroke-groups,
// 8 waves. Stage A = bulk copy of the row's lists/headers from ws (L2/L3).
// Stage B + combine are verbatim r10 (18.08us kernel).
// ---------------------------------------------------------------------------
__global__ __launch_bounds__(512, 8) void raster_kernel(
    const float2* __restrict__ ws_list,
    const float4* __restrict__ ws_hdr,
    const float* __restrict__ colors,    // (64,3)
    float* __restrict__ out)             // (1,3,512,512)
{
    __shared__ __align__(16) float2 slist[NSTROKES * LSTRIDE];  // 32 KB
    __shared__ float4 scull[NSTROKES];   // xmin-cut, xmax+cut, w, cnt
    __shared__ float4 scol [NSTROKES];   // r,g,b,pad

    const int tid  = threadIdx.x;
    const int wave = tid >> 6;           // 0..7
    const int lane = tid & 63;
    const int pxl  = tid & 255;          // pixel within half-row
    const int grp  = tid >> 8;           // 0: strokes 0-31, 1: strokes 32-63
    const int row  = blockIdx.x >> 1;
    const int half = blockIdx.x & 1;
    const float fy = (float)row;

    // ---- stage A: copy this row's lists + headers into LDS
    const size_t rbase = (size_t)row * NSTROKES;
    #pragma unroll
    for (int i = 0; i < 8; ++i) {
        const int s = wave * 8 + i;
        slist[s * LSTRIDE + lane] = ws_list[(rbase + s) * LSTRIDE + lane];
    }
    if (lane < 8) scull[wave * 8 + lane] = ws_hdr[rbase + wave * 8 + lane];
    if (tid < NSTROKES)
        scol[tid] = make_float4(colors[3*tid], colors[3*tid+1],
                                colors[3*tid+2], 0.0f);
    __syncthreads();

    // ---- stage B (r10 verbatim): 2 strokes in flight per iteration
    const float fx      = (float)(half * 256 + pxl);
    const float span_lo = (float)(half * 256 + ((wave & 3) << 6));
    const float span_hi = span_lo + 63.0f;
    const int   sbase   = grp << 5;

    float4 cbl = scull[sbase + (lane & 31)];
    bool alive = (cbl.w > 0.0f) && (cbl.x <= span_hi) && (cbl.y >= span_lo);
    unsigned int live = (unsigned int)__ballot(alive);   // low 32 == high 32

    float A = 1.0f, br = 0.0f, bg = 0.0f, bb = 0.0f;

    while (live) {
        const int s0 = sbase + (__ffs(live) - 1);
        live &= live - 1u;
        const bool has1 = (live != 0u);
        const int s1 = has1 ? (sbase + (__ffs(live) - 1)) : s0;
        if (has1) live &= live - 1u;

        float4 cb0  = scull[s0];
        float4 cb1  = scull[s1];
        float4 col0 = scol [s0];
        float4 col1 = scol [s1];
        const int   kc0 = (int)cb0.w;
        const int   kc1 = has1 ? (int)cb1.w : 0;
        const float w0  = cb0.z;
        const float w1  = cb1.z;

        float m0 = 1e30f, m1 = 1e30f;
        const float4* L0 = (const float4*)(slist + s0 * LSTRIDE);
        const float4* L1 = (const float4*)(slist + s1 * LSTRIDE);

        const int kmax = kc0 > kc1 ? kc0 : kc1;
        for (int j = 0; j < kmax; j += 4) {        // sentinel-padded to 4
            if (j < kc0) {                          // wave-uniform branch
                float4 q0 = L0[(j >> 1)];
                float4 q1 = L0[(j >> 1) + 1];
                float dy0 = fy - q0.y, dy1 = fy - q0.w;
                float dy2 = fy - q1.y, dy3 = fy - q1.w;
                float d0  = fx - q0.x, d1  = fx - q0.z;
                float d2  = fx - q1.x, d3  = fx - q1.z;
                float a01 = fminf(fmaf(d0, d0, dy0*dy0), fmaf(d1, d1, dy1*dy1));
                float a23 = fminf(fmaf(d2, d2, dy2*dy2), fmaf(d3, d3, dy3*dy3));
                m0 = fminf(fminf(a01, a23), m0);
            }
            if (j < kc1) {
                float4 q0 = L1[(j >> 1)];
                float4 q1 = L1[(j >> 1) + 1];
                float dy0 = fy - q0.y, dy1 = fy - q0.w;
                float dy2 = fy - q1.y, dy3 = fy - q1.w;
                float d0  = fx - q0.x, d1  = fx - q0.z;
                float d2  = fx - q1.x, d3  = fx - q1.z;
                float a01 = fminf(fmaf(d0, d0, dy0*dy0), fmaf(d1, d1, dy1*dy1));
                float a23 = fminf(fmaf(d2, d2, dy2*dy2), fmaf(d3, d3, dy3*dy3));
                m1 = fminf(fminf(a01, a23), m1);
            }
        }

        float al0 = __builtin_amdgcn_rcpf(1.0f + __expf(2.0f * (sqrtf(m0) - w0)));
        float al1 = __builtin_amdgcn_rcpf(1.0f + __expf(2.0f * (sqrtf(m1) - w1)));

        A  *= (1.0f - al0);
        br  = fmaf(al0, col0.x - br, br);
        bg  = fmaf(al0, col0.y - bg, bg);
        bb  = fmaf(al0, col0.z - bb, bb);
        if (has1) {
            A  *= (1.0f - al1);
            br  = fmaf(al1, col1.x - br, br);
            bg  = fmaf(al1, col1.y - bg, bg);
            bb  = fmaf(al1, col1.z - bb, bb);
        }
    }

    // ---- combine: g0 publishes (A,B) via LDS (slist is dead), g1 folds
    __syncthreads();
    float4* xfer = (float4*)slist;           // 256 x float4
    if (grp == 0) {
        xfer[pxl] = make_float4(A, br, bg, bb);
    }
    __syncthreads();
    if (grp == 1) {
        float4 g0 = xfer[pxl];
        // white canvas: c0 = A0*1 + B0; then c = A1*c0 + B1
        float cr = fmaf(A, g0.x + g0.y, br);
        float cg = fmaf(A, g0.x + g0.z, bg);
        float cb = fmaf(A, g0.x + g0.w, bb);
        const int base = row * CANVAS + half * 256 + pxl;
        out[0*HW + base] = cr;
        out[1*HW + base] = cg;
        out[2*HW + base] = cb;
    }
}

// ---------------------------------------------------------------------------
// Fallback (ws too small): round-10 fused kernel, known-good 18.08us.
// ---------------------------------------------------------------------------
__global__ __launch_bounds__(1024, 8) void raster_fused_fallback(
    const float* __restrict__ strokes, const float* __restrict__ widths,
    const float* __restrict__ colors, float* __restrict__ out)
{
    __shared__ __align__(16) float2 slist[NSTROKES * LSTRIDE];
    __shared__ float4 scull[NSTROKES];
    __shared__ float4 scol [NSTROKES];

    const int tid  = threadIdx.x;
    const int wave = tid >> 6;
    const int lane = tid & 63;
    const int px   = tid & 511;
    const int grp  = tid >> 9;
    const int y    = blockIdx.x;
    const float fy = (float)y;

    #pragma unroll
    for (int i = 0; i < 4; ++i) {
        const int s = wave * 4 + i;
        float4 a = ((const float4*)strokes)[s * 2];
        float4 b = ((const float4*)strokes)[s * 2 + 1];
        const float S = (float)CANVAS;
        float c0x = a.x * S;
        float c1x = 3.0f * (a.z - a.x) * S;
        float c2x = 3.0f * (b.x - 2.0f * a.z + a.x) * S;
        float c3x = (b.z - 3.0f * b.x + 3.0f * a.z - a.x) * S;
        float c0y = a.y * S;
        float c1y = 3.0f * (a.w - a.y) * S;
        float c2y = 3.0f * (b.y - 2.0f * a.w + a.y) * S;
        float c3y = (b.w - 3.0f * b.y + 3.0f * a.w - a.y) * S;

        float w   = widths[s];
        float cut = w + 10.0f;

        float t   = (float)lane * (1.0f / (float)(NSAMP - 1));
        float px_ = fmaf(fmaf(fmaf(c3x, t, c2x), t, c1x), t, c0x);
        float py_ = fmaf(fmaf(fmaf(c3y, t, c2y), t, c1y), t, c0y);

        bool keep = (lane < NSAMP) && (fabsf(py_ - fy) <= cut);
        unsigned long long mask = __ballot(keep);
        int idx = __popcll(mask & ((1ull << lane) - 1ull));
        if (keep) {
            slist[s * LSTRIDE + idx] = make_float2(px_, py_);
        } else if (lane >= NSAMP) {
            slist[s * LSTRIDE + idx + (lane - NSAMP)] = make_float2(1e15f, 1e15f);
        }

        if (mask) {
            float vmn = keep ? px_ : 1e30f;
            float vmx = keep ? px_ : -1e30f;
            #pragma unroll
            for (int off = 32; off; off >>= 1) {
                vmn = fminf(vmn, __shfl_xor(vmn, off));
                vmx = fmaxf(vmx, __shfl_xor(vmx, off));
            }
            if (lane == 0) {
                scull[s] = make_float4(vmn - cut, vmx + cut, w,
                                       (float)__popcll(mask));
                scol [s] = make_float4(colors[3*s], colors[3*s+1],
                                       colors[3*s+2], 0.0f);
            }
        } else if (lane == 0) {
            scull[s] = make_float4(0.0f, 0.0f, w, 0.0f);
        }
    }
    __syncthreads();

    const float fx      = (float)px;
    const float span_lo = (float)((wave & 7) << 6);
    const float span_hi = span_lo + 63.0f;
    const int   sbase   = grp << 5;

    float4 cbl = scull[sbase + (lane & 31)];
    bool alive = (cbl.w > 0.0f) && (cbl.x <= span_hi) && (cbl.y >= span_lo);
    unsigned int live = (unsigned int)__ballot(alive);

    float A = 1.0f, br = 0.0f, bg = 0.0f, bb = 0.0f;

    while (live) {
        const int s0 = sbase + (__ffs(live) - 1);
        live &= live - 1u;
        const bool has1 = (live != 0u);
        const int s1 = has1 ? (sbase + (__ffs(live) - 1)) : s0;
        if (has1) live &= live - 1u;

        float4 cb0  = scull[s0];
        float4 cb1  = scull[s1];
        float4 col0 = scol [s0];
        float4 col1 = scol [s1];
        const int   kc0 = (int)cb0.w;
        const int   kc1 = has1 ? (int)cb1.w : 0;
        const float w0  = cb0.z;
        const float w1  = cb1.z;

        float m0 = 1e30f, m1 = 1e30f;
        const float4* L0 = (const float4*)(slist + s0 * LSTRIDE);
        const float4* L1 = (const float4*)(slist + s1 * LSTRIDE);

        const int kmax = kc0 > kc1 ? kc0 : kc1;
        for (int j = 0; j < kmax; j += 4) {
            if (j < kc0) {
                float4 q0 = L0[(j >> 1)];
                float4 q1 = L0[(j >> 1) + 1];
                float dy0 = fy - q0.y, dy1 = fy - q0.w;
                float dy2 = fy - q1.y, dy3 = fy - q1.w;
                float d0  = fx - q0.x, d1  = fx - q0.z;
                float d2  = fx - q1.x, d3  = fx - q1.z;
                float a01 = fminf(fmaf(d0, d0, dy0*dy0), fmaf(d1, d1, dy1*dy1));
                float a23 = fminf(fmaf(d2, d2, dy2*dy2), fmaf(d3, d3, dy3*dy3));
                m0 = fminf(fminf(a01, a23), m0);
            }
            if (j < kc1) {
                float4 q0 = L1[(j >> 1)];
                float4 q1 = L1[(j >> 1) + 1];
                float dy0 = fy - q0.y, dy1 = fy - q0.w;
                float dy2 = fy - q1.y, dy3 = fy - q1.w;
                float d0  = fx - q0.x, d1  = fx - q0.z;
                float d2  = fx - q1.x, d3  = fx - q1.z;
                float a01 = fminf(fmaf(d0, d0, dy0*dy0), fmaf(d1, d1, dy1*dy1));
                float a23 = fminf(fmaf(d2, d2, dy2*dy2), fmaf(d3, d3, dy3*dy3));
                m1 = fminf(fminf(a01, a23), m1);
            }
        }

        float al0 = __builtin_amdgcn_rcpf(1.0f + __expf(2.0f * (sqrtf(m0) - w0)));
        float al1 = __builtin_amdgcn_rcpf(1.0f + __expf(2.0f * (sqrtf(m1) - w1)));

        A  *= (1.0f - al0);
        br  = fmaf(al0, col0.x - br, br);
        bg  = fmaf(al0, col0.y - bg, bg);
        bb  = fmaf(al0, col0.z - bb, bb);
        if (has1) {
            A  *= (1.0f - al1);
            br  = fmaf(al1, col1.x - br, br);
            bg  = fmaf(al1, col1.y - bg, bg);
            bb  = fmaf(al1, col1.z - bb, bb);
        }
    }

    __syncthreads();
    float4* xfer = (float4*)slist;
    if (grp == 0) {
        xfer[px] = make_float4(A, br, bg, bb);
    }
    __syncthreads();
    if (grp == 1) {
        float4 g0 = xfer[px];
        float cr = fmaf(A, g0.x + g0.y, br);
        float cg = fmaf(A, g0.x + g0.z, bg);
        float cb = fmaf(A, g0.x + g0.w, bb);
        const int base = y * CANVAS + px;
        out[0*HW + base] = cr;
        out[1*HW + base] = cg;
        out[2*HW + base] = cb;
    }
}

extern "C" void kernel_launch(void* const* d_in, const int* in_sizes, int n_in,
                              void* d_out, int out_size, void* d_ws, size_t ws_size,
                              hipStream_t stream) {
    const float* strokes = (const float*)d_in[0];
    const float* widths  = (const float*)d_in[1];
    const float* colors  = (const float*)d_in[2];
    float* out = (float*)d_out;

    if (ws_size >= WS_NEED) {
        float2* ws_list = (float2*)d_ws;
        float4* ws_hdr  = (float4*)((char*)d_ws + WS_LIST_BYTES);
        sample_kernel<<<dim3((CANVAS * NSTROKES) / 256), dim3(256), 0, stream>>>(
            strokes, widths, ws_list, ws_hdr);
        raster_kernel<<<dim3(CANVAS * 2), dim3(512), 0, stream>>>(
            ws_list, ws_hdr, colors, out);
    } else {
        raster_fused_fallback<<<dim3(CANVAS), dim3(1024), 0, stream>>>(
            strokes, widths, colors, out);
    }
}

// Round 17
// 17.342 us; speedup vs baseline: 1.8254x; 1.2469x over previous
//
#include <hip/hip_runtime.h>

#define NSTROKES 64
#define NSAMP    50
#define CANVAS   512
#define HW       (CANVAS * CANVAS)
#define TPB      1024                  // 512 px x 2 stroke-groups, 16 waves
#define SPW      (NSTROKES / 16)       // 4 strokes per wave (stage A)
#define LSTRIDE  64                    // float2 slots per stroke list

// ---------------------------------------------------------------------------
// Single kernel, one block per canvas row (r10 structure, consolidated).
//  tid = px + 512*grp; grp g composites strokes g*32..g*32+31 (affine map
//  c -> A*c + B), folded via a DEDICATED xfer buffer (one barrier, no slist
//  aliasing): c = A1*(A0*white + B0) + B1.
//  stage A: ballot compaction. NEW: lists store (px, dy^2) -- dy depends only
//  on (sample,row), so squaring it once in stage A removes 8 of ~19 VALU ops
//  per 4-sample stage-B iteration. Arithmetic on the stage-B side is
//  fmaf(d,d,dy2) exactly as before -> bit-identical output.
//  stage B: r10 verbatim otherwise (interval cull, 2 strokes in flight).
// ---------------------------------------------------------------------------
__global__ __launch_bounds__(TPB, 8) void raster_fused_kernel(
    const float* __restrict__ strokes,   // (64,4,2)
    const float* __restrict__ widths,    // (64,)
    const float* __restrict__ colors,    // (64,3)
    float* __restrict__ out)             // (1,3,512,512)
{
    __shared__ __align__(16) float2 slist[NSTROKES * LSTRIDE];  // 32 KB
    __shared__ float4 scull[NSTROKES];   // xmin-cut, xmax+cut, w, cnt
    __shared__ float4 scol [NSTROKES];   // r,g,b,pad
    __shared__ float4 xfer [512];        // dedicated combine buffer (8 KB)

    const int tid  = threadIdx.x;
    const int wave = tid >> 6;
    const int lane = tid & 63;
    const int px   = tid & 511;
    const int grp  = tid >> 9;           // 0: strokes 0-31, 1: strokes 32-63
    const int y    = blockIdx.x;
    const float fy = (float)y;

    // ---- stage A: compaction, SPW strokes per wave, lane = sample index
    #pragma unroll
    for (int i = 0; i < SPW; ++i) {
        const int s = wave * SPW + i;        // stroke id 0..63

        float4 a = ((const float4*)strokes)[s * 2];       // p0x,p0y,p1x,p1y
        float4 b = ((const float4*)strokes)[s * 2 + 1];   // p2x,p2y,p3x,p3y
        const float S = (float)CANVAS;
        float c0x = a.x * S;
        float c1x = 3.0f * (a.z - a.x) * S;
        float c2x = 3.0f * (b.x - 2.0f * a.z + a.x) * S;
        float c3x = (b.z - 3.0f * b.x + 3.0f * a.z - a.x) * S;
        float c0y = a.y * S;
        float c1y = 3.0f * (a.w - a.y) * S;
        float c2y = 3.0f * (b.y - 2.0f * a.w + a.y) * S;
        float c3y = (b.w - 3.0f * b.y + 3.0f * a.w - a.y) * S;

        float w   = widths[s];
        float cut = w + 10.0f;               // alpha <= sigmoid(-20) ~ 2e-9 beyond

        float t   = (float)lane * (1.0f / (float)(NSAMP - 1));
        float px_ = fmaf(fmaf(fmaf(c3x, t, c2x), t, c1x), t, c0x);
        float py_ = fmaf(fmaf(fmaf(c3y, t, c2y), t, c1y), t, c0y);

        float dy  = py_ - fy;
        bool keep = (lane < NSAMP) && (fabsf(dy) <= cut);
        unsigned long long mask = __ballot(keep);
        int idx = __popcll(mask & ((1ull << lane) - 1ull));
        if (keep) {
            slist[s * LSTRIDE + idx] = make_float2(px_, dy * dy);  // (px, dy^2)
        } else if (lane >= NSAMP) {
            // lanes 50..63: idx == kc for all -> consecutive sentinel slots
            slist[s * LSTRIDE + idx + (lane - NSAMP)] = make_float2(1e15f, 1e15f);
        }

        if (mask) {
            float vmn = keep ? px_ : 1e30f;
            float vmx = keep ? px_ : -1e30f;
            #pragma unroll
            for (int off = 32; off; off >>= 1) {
                vmn = fminf(vmn, __shfl_xor(vmn, off));
                vmx = fmaxf(vmx, __shfl_xor(vmx, off));
            }
            if (lane == 0) {
                scull[s] = make_float4(vmn - cut, vmx + cut, w,
                                       (float)__popcll(mask));
                scol [s] = make_float4(colors[3*s], colors[3*s+1],
                                       colors[3*s+2], 0.0f);
            }
        } else if (lane == 0) {
            scull[s] = make_float4(0.0f, 0.0f, w, 0.0f);   // cnt=0 -> culled
        }
    }
    __syncthreads();

    // ---- stage B: lane l tests stroke grp*32+(l&31); 32-bit live mask
    const float fx      = (float)px;
    const float span_lo = (float)((wave & 7) << 6);
    const float span_hi = span_lo + 63.0f;
    const int   sbase   = grp << 5;

    float4 cbl = scull[sbase + (lane & 31)];
    bool alive = (cbl.w > 0.0f) && (cbl.x <= span_hi) && (cbl.y >= span_lo);
    unsigned int live = (unsigned int)__ballot(alive);   // low 32 == high 32

    float A = 1.0f, br = 0.0f, bg = 0.0f, bb = 0.0f;

    while (live) {
        // pop up to TWO live strokes (ascending ids: composite order kept)
        const int s0 = sbase + (__ffs(live) - 1);
        live &= live - 1u;
        const bool has1 = (live != 0u);
        const int s1 = has1 ? (sbase + (__ffs(live) - 1)) : s0;
        if (has1) live &= live - 1u;

        // independent LDS reads issue back-to-back (2x MLP)
        float4 cb0  = scull[s0];
        float4 cb1  = scull[s1];
        float4 col0 = scol [s0];
        float4 col1 = scol [s1];
        const int   kc0 = (int)cb0.w;
        const int   kc1 = has1 ? (int)cb1.w : 0;
        const float w0  = cb0.z;
        const float w1  = cb1.z;

        float m0 = 1e30f, m1 = 1e30f;
        const float4* L0 = (const float4*)(slist + s0 * LSTRIDE);
        const float4* L1 = (const float4*)(slist + s1 * LSTRIDE);

        const int kmax = kc0 > kc1 ? kc0 : kc1;
        for (int j = 0; j < kmax; j += 4) {        // sentinel-padded to 4
            if (j < kc0) {                          // wave-uniform branch
                float4 q0 = L0[(j >> 1)];           // (px,dy2, px,dy2)
                float4 q1 = L0[(j >> 1) + 1];
                float d0 = fx - q0.x, d1 = fx - q0.z;
                float d2 = fx - q1.x, d3 = fx - q1.z;
                float a01 = fminf(fmaf(d0, d0, q0.y), fmaf(d1, d1, q0.w));
                float a23 = fminf(fmaf(d2, d2, q1.y), fmaf(d3, d3, q1.w));
                m0 = fminf(fminf(a01, a23), m0);
            }
            if (j < kc1) {                          // wave-uniform branch
                float4 q0 = L1[(j >> 1)];
                float4 q1 = L1[(j >> 1) + 1];
                float d0 = fx - q0.x, d1 = fx - q0.z;
                float d2 = fx - q1.x, d3 = fx - q1.z;
                float a01 = fminf(fmaf(d0, d0, q0.y), fmaf(d1, d1, q0.w));
                float a23 = fminf(fmaf(d2, d2, q1.y), fmaf(d3, d3, q1.w));
                m1 = fminf(fminf(a01, a23), m1);
            }
        }

        // both alphas compute with ILP; blend strictly s0 then s1
        float al0 = __builtin_amdgcn_rcpf(1.0f + __expf(2.0f * (sqrtf(m0) - w0)));
        float al1 = __builtin_amdgcn_rcpf(1.0f + __expf(2.0f * (sqrtf(m1) - w1)));

        A  *= (1.0f - al0);
        br  = fmaf(al0, col0.x - br, br);
        bg  = fmaf(al0, col0.y - bg, bg);
        bb  = fmaf(al0, col0.z - bb, bb);
        if (has1) {
            A  *= (1.0f - al1);
            br  = fmaf(al1, col1.x - br, br);
            bg  = fmaf(al1, col1.y - bg, bg);
            bb  = fmaf(al1, col1.z - bb, bb);
        }
    }

    // ---- combine: g0 publishes immediately (dedicated buffer), ONE barrier
    if (grp == 0) {
        xfer[px] = make_float4(A, br, bg, bb);
    }
    __syncthreads();
    if (grp == 1) {
        float4 g0 = xfer[px];
        // white canvas: c0 = A0*1 + B0; then c = A1*c0 + B1
        float cr = fmaf(A, g0.x + g0.y, br);
        float cg = fmaf(A, g0.x + g0.z, bg);
        float cb = fmaf(A, g0.x + g0.w, bb);
        const int base = y * CANVAS + px;
        out[0*HW + base] = cr;
        out[1*HW + base] = cg;
        out[2*HW + base] = cb;
    }
}

extern "C" void kernel_launch(void* const* d_in, const int* in_sizes, int n_in,
                              void* d_out, int out_size, void* d_ws, size_t ws_size,
                              hipStream_t stream) {
    const float* strokes = (const float*)d_in[0];
    const float* widths  = (const float*)d_in[1];
    const float* colors  = (const float*)d_in[2];
    float* out = (float*)d_out;

    raster_fused_kernel<<<dim3(CANVAS), dim3(TPB), 0, stream>>>(
        strokes, widths, colors, out);
}